// Round 8
// baseline (121.269 us; speedup 1.0000x reference)
//
#include <hip/hip_runtime.h>
#include <hip/hip_fp16.h>

#define N_NODES 100000
#define N_EDGES 1600000
#define D_FEAT 64

typedef __attribute__((ext_vector_type(4))) _Float16 half4v;
typedef __attribute__((ext_vector_type(8))) _Float16 half8v;

// ---------------------------------------------------------------------------
// Prep (fused): part A converts x (fp32) -> xh (fp16, 128B rows);
//               part B builds CSR row_ptr from sorted target_index.
// ---------------------------------------------------------------------------
__global__ __launch_bounds__(256) void prep_kernel(
    const float4* __restrict__ x4,   // [N_NODES*16]
    const int*    __restrict__ tgt,  // [N_EDGES] sorted
    half4v*       __restrict__ xh,   // [N_NODES*16]
    int*          __restrict__ row_ptr,
    int conv_blocks)
{
    const int bid = blockIdx.x;
    if (bid < conv_blocks) {
        int i = bid * 256 + threadIdx.x;       // one float4 -> one half4
        if (i < N_NODES * 16) {
            float4 v = x4[i];
            half4v h;
            h.x = (_Float16)v.x; h.y = (_Float16)v.y;
            h.z = (_Float16)v.z; h.w = (_Float16)v.w;
            xh[i] = h;
        }
    } else {
        int e = (bid - conv_blocks) * 256 + threadIdx.x;
        if (e >= N_EDGES) return;
        int cur = tgt[e];
        int lo  = (e == 0) ? 0 : tgt[e - 1] + 1;
        for (int n = lo; n <= cur; ++n) row_ptr[n] = e;
        if (e == N_EDGES - 1) {
            for (int n = cur + 1; n <= N_NODES; ++n) row_ptr[n] = N_EDGES;
        }
    }
}

// Standalone row_ptr build (fallback path)
__global__ __launch_bounds__(256) void build_row_ptr(
    const int* __restrict__ tgt, int* __restrict__ row_ptr)
{
    int e = blockIdx.x * blockDim.x + threadIdx.x;
    if (e >= N_EDGES) return;
    int cur = tgt[e];
    int lo  = (e == 0) ? 0 : tgt[e - 1] + 1;
    for (int n = lo; n <= cur; ++n) row_ptr[n] = e;
    if (e == N_EDGES - 1) {
        for (int n = cur + 1; n <= N_NODES; ++n) row_ptr[n] = N_EDGES;
    }
}

// ---------------------------------------------------------------------------
// Gather-sum over fp16 rows: one 8-LANE group owns one node end-to-end.
// Lane owns 8 features (16B half8v gather per edge). 32 groups per 256-block
// -> 12.5k waves (full 8 waves/SIMD occupancy). Per 32-edge block: (src,ev)
// staged to LDS (2 ds_write_b128/lane), then chunks of 4 edges with a 2-deep
// pipeline: 4 gathers in flight x 2 stages x 8 groups = 64 outstanding/wave.
// Weights re-read from LDS at consume (broadcast) to keep VGPR <= 64.
// Slots past the node's degree: clamped source (harmless), weight forced 0.
// ---------------------------------------------------------------------------
#define GPB        32    // 8-lane groups per block
#define LDS_STRIDE 272   // 32 slots * 8B + 16B pad

__global__ __launch_bounds__(256, 8) void gather_sum_h(
    const half8v* __restrict__ xh8,      // [N_NODES, 8] half8
    const float*  __restrict__ ev,
    const int*    __restrict__ src,
    const int*    __restrict__ row_ptr,
    float4*       __restrict__ out4)     // [N_NODES, 16] float4
{
    __shared__ char lds_raw[GPB * LDS_STRIDE];

    const int tib  = threadIdx.x;
    const int gib  = tib >> 3;          // group within block: 0..31
    const int lane = tib & 7;           // lane within group: 0..7
    const int node = blockIdx.x * GPB + gib;
    if (node >= N_NODES) return;

    char* gbase = lds_raw + gib * LDS_STRIDE;

    const int start = row_ptr[node];
    const int end   = row_ptr[node + 1];

    float4 accA = make_float4(0.f, 0.f, 0.f, 0.f);
    float4 accB = make_float4(0.f, 0.f, 0.f, 0.f);

#define ACC8(W, X) do { \
        accA.x = fmaf((W), (float)(X)[0], accA.x); \
        accA.y = fmaf((W), (float)(X)[1], accA.y); \
        accA.z = fmaf((W), (float)(X)[2], accA.z); \
        accA.w = fmaf((W), (float)(X)[3], accA.w); \
        accB.x = fmaf((W), (float)(X)[4], accB.x); \
        accB.y = fmaf((W), (float)(X)[5], accB.y); \
        accB.z = fmaf((W), (float)(X)[6], accB.z); \
        accB.w = fmaf((W), (float)(X)[7], accB.w); } while (0)

    for (int blk = start; blk < end; blk += 32) {
        // ---- stage 32 edges: lane handles slots 4*lane..4*lane+3
        {
            const int e0   = blk + 4 * lane;
            const int emax = end - 1;
            int c0 = e0     < emax ? e0     : emax;
            int c1 = e0 + 1 < emax ? e0 + 1 : emax;
            int c2 = e0 + 2 < emax ? e0 + 2 : emax;
            int c3 = e0 + 3 < emax ? e0 + 3 : emax;
            int s0 = src[c0], s1 = src[c1], s2 = src[c2], s3 = src[c3];
            float w0 = ev[c0], w1 = ev[c1], w2 = ev[c2], w3 = ev[c3];
            w0 = (e0     < end) ? w0 : 0.0f;
            w1 = (e0 + 1 < end) ? w1 : 0.0f;
            w2 = (e0 + 2 < end) ? w2 : 0.0f;
            w3 = (e0 + 3 < end) ? w3 : 0.0f;
            ((int4*)gbase)[2 * lane]     =
                make_int4(s0, __float_as_int(w0), s1, __float_as_int(w1));
            ((int4*)gbase)[2 * lane + 1] =
                make_int4(s2, __float_as_int(w2), s3, __float_as_int(w3));
        }

        const int rem = end - blk;
        const int nch = ((rem < 32 ? rem : 32) + 3) >> 2;   // chunks of 4 edges

        // ---- chunk 0: addresses + 4 gathers
        int4 p0 = ((const int4*)gbase)[0];
        int4 p1 = ((const int4*)gbase)[1];
        half8v xa0 = xh8[p0.x * 8 + lane];
        half8v xb0 = xh8[p0.z * 8 + lane];
        half8v xc0 = xh8[p1.x * 8 + lane];
        half8v xd0 = xh8[p1.z * 8 + lane];

        for (int c = 1; c < nch; ++c) {
            // issue next chunk's gathers first
            int4 q0 = ((const int4*)gbase)[2 * c];
            int4 q1 = ((const int4*)gbase)[2 * c + 1];
            half8v xa1 = xh8[q0.x * 8 + lane];
            half8v xb1 = xh8[q0.z * 8 + lane];
            half8v xc1 = xh8[q1.x * 8 + lane];
            half8v xd1 = xh8[q1.z * 8 + lane];

            // consume current chunk (weights re-read: broadcast ds_read)
            int4 m0 = ((const int4*)gbase)[2 * (c - 1)];
            int4 m1 = ((const int4*)gbase)[2 * (c - 1) + 1];
            ACC8(__int_as_float(m0.y), xa0);
            ACC8(__int_as_float(m0.w), xb0);
            ACC8(__int_as_float(m1.y), xc0);
            ACC8(__int_as_float(m1.w), xd0);

            xa0 = xa1; xb0 = xb1; xc0 = xc1; xd0 = xd1;
        }

        // consume final chunk
        int4 m0 = ((const int4*)gbase)[2 * (nch - 1)];
        int4 m1 = ((const int4*)gbase)[2 * (nch - 1) + 1];
        ACC8(__int_as_float(m0.y), xa0);
        ACC8(__int_as_float(m0.w), xb0);
        ACC8(__int_as_float(m1.y), xc0);
        ACC8(__int_as_float(m1.w), xd0);
    }
#undef ACC8

    // lane owns features [8*lane, 8*lane+8) -> two float4 stores, 256B/row
    out4[node * 16 + lane * 2]     = accA;
    out4[node * 16 + lane * 2 + 1] = accB;
}

// fp32 fallback gather (R3 structure) if ws can't hold xh
__global__ __launch_bounds__(256) void gather_sum_f32(
    const float4* __restrict__ x4,
    const float*  __restrict__ ev,
    const int*    __restrict__ src,
    const int*    __restrict__ row_ptr,
    float4*       __restrict__ out4)
{
    const int node = blockIdx.x * 4 + (threadIdx.x >> 6);
    if (node >= N_NODES) return;
    const int lane = threadIdx.x & 63;
    const int g    = lane >> 4;
    const int f    = lane & 15;

    const int start = row_ptr[node];
    const int end   = row_ptr[node + 1];

    float4 acc = make_float4(0.f, 0.f, 0.f, 0.f);
    if (start < end) {
        int  ea = start + g, eb = start + 4 + g;
        bool va = ea < end,  vb = eb < end;
        int  esa = va ? ea : start, esb = vb ? eb : start;
        float wa = va ? ev[esa] : 0.0f;
        float wb = vb ? ev[esb] : 0.0f;
        int   sa = src[esa];
        int   sb = src[esb];

        for (int e0 = start; e0 < end; e0 += 8) {
            const float4 xa = x4[sa * 16 + f];
            const float4 xb = x4[sb * 16 + f];
            const float cwa = wa, cwb = wb;
            {
                int  na = e0 + 8 + g, nb = e0 + 12 + g;
                bool vna = na < end,  vnb = nb < end;
                int  nsa = vna ? na : start, nsb = vnb ? nb : start;
                wa = vna ? ev[nsa] : 0.0f;
                wb = vnb ? ev[nsb] : 0.0f;
                sa = src[nsa];
                sb = src[nsb];
            }
            acc.x = fmaf(cwa, xa.x, acc.x);
            acc.y = fmaf(cwa, xa.y, acc.y);
            acc.z = fmaf(cwa, xa.z, acc.z);
            acc.w = fmaf(cwa, xa.w, acc.w);
            acc.x = fmaf(cwb, xb.x, acc.x);
            acc.y = fmaf(cwb, xb.y, acc.y);
            acc.z = fmaf(cwb, xb.z, acc.z);
            acc.w = fmaf(cwb, xb.w, acc.w);
        }
    }
    acc.x += __shfl_xor(acc.x, 16, 64);
    acc.y += __shfl_xor(acc.y, 16, 64);
    acc.z += __shfl_xor(acc.z, 16, 64);
    acc.w += __shfl_xor(acc.w, 16, 64);
    acc.x += __shfl_xor(acc.x, 32, 64);
    acc.y += __shfl_xor(acc.y, 32, 64);
    acc.z += __shfl_xor(acc.z, 32, 64);
    acc.w += __shfl_xor(acc.w, 32, 64);
    if (g == 0) out4[node * 16 + f] = acc;
}

extern "C" void kernel_launch(void* const* d_in, const int* in_sizes, int n_in,
                              void* d_out, int out_size, void* d_ws, size_t ws_size,
                              hipStream_t stream) {
    const float* x            = (const float*)d_in[0];
    const float* edge_values  = (const float*)d_in[1];
    const int*   target_index = (const int*)d_in[2];
    const int*   source_index = (const int*)d_in[3];
    float*       out          = (float*)d_out;

    const size_t rp_bytes = (size_t)(N_NODES + 1) * sizeof(int);
    const size_t xh_off   = (rp_bytes + 511) & ~(size_t)511;
    const size_t xh_bytes = (size_t)N_NODES * D_FEAT * sizeof(_Float16); // 12.8 MB
    const size_t need     = xh_off + xh_bytes;

    int* row_ptr = (int*)d_ws;

    if (ws_size >= need) {
        half4v* xh = (half4v*)((char*)d_ws + xh_off);
        const int conv_blocks = (N_NODES * 16 + 255) / 256;          // 6250
        const int rp_blocks   = (N_EDGES + 255) / 256;               // 6250
        prep_kernel<<<conv_blocks + rp_blocks, 256, 0, stream>>>(
            (const float4*)x, target_index, xh, row_ptr, conv_blocks);

        const int n_blocks = (N_NODES + GPB - 1) / GPB;              // 3125
        gather_sum_h<<<n_blocks, 256, 0, stream>>>(
            (const half8v*)xh, edge_values, source_index, row_ptr, (float4*)out);
    } else {
        build_row_ptr<<<(N_EDGES + 255) / 256, 256, 0, stream>>>(target_index, row_ptr);
        gather_sum_f32<<<(N_NODES + 3) / 4, 256, 0, stream>>>(
            (const float4*)x, edge_values, source_index, row_ptr, (float4*)out);
    }
}

// Round 9
// 121.194 us; speedup vs baseline: 1.0006x; 1.0006x over previous
//
#include <hip/hip_runtime.h>
#include <hip/hip_fp16.h>

#define N_NODES 100000
#define N_EDGES 1600000
#define D_FEAT 64

typedef __attribute__((ext_vector_type(4))) _Float16 half4v;

// ---------------------------------------------------------------------------
// Prep (fused): part A converts x (fp32) -> xh (fp16, 128B rows);
//               part B builds CSR row_ptr from sorted target_index.
// ---------------------------------------------------------------------------
__global__ __launch_bounds__(256) void prep_kernel(
    const float4* __restrict__ x4,   // [N_NODES*16]
    const int*    __restrict__ tgt,  // [N_EDGES] sorted
    half4v*       __restrict__ xh,   // [N_NODES*16]
    int*          __restrict__ row_ptr,
    int conv_blocks)
{
    const int bid = blockIdx.x;
    if (bid < conv_blocks) {
        int i = bid * 256 + threadIdx.x;       // one float4 -> one half4
        if (i < N_NODES * 16) {
            float4 v = x4[i];
            half4v h;
            h.x = (_Float16)v.x; h.y = (_Float16)v.y;
            h.z = (_Float16)v.z; h.w = (_Float16)v.w;
            xh[i] = h;
        }
    } else {
        int e = (bid - conv_blocks) * 256 + threadIdx.x;
        if (e >= N_EDGES) return;
        int cur = tgt[e];
        int lo  = (e == 0) ? 0 : tgt[e - 1] + 1;
        for (int n = lo; n <= cur; ++n) row_ptr[n] = e;
        if (e == N_EDGES - 1) {
            for (int n = cur + 1; n <= N_NODES; ++n) row_ptr[n] = N_EDGES;
        }
    }
}

// Standalone row_ptr build (fallback path)
__global__ __launch_bounds__(256) void build_row_ptr(
    const int* __restrict__ tgt, int* __restrict__ row_ptr)
{
    int e = blockIdx.x * blockDim.x + threadIdx.x;
    if (e >= N_EDGES) return;
    int cur = tgt[e];
    int lo  = (e == 0) ? 0 : tgt[e - 1] + 1;
    for (int n = lo; n <= cur; ++n) row_ptr[n] = e;
    if (e == N_EDGES - 1) {
        for (int n = cur + 1; n <= N_NODES; ++n) row_ptr[n] = N_EDGES;
    }
}

// ---------------------------------------------------------------------------
// Gather-sum over fp16 rows: one 16-lane group owns one node end-to-end.
// (Best-measured variant: 120.4 us total.) No cross-group reduction,
// unconditional float4 store per group. Per 16-edge block: (src,ev) staged
// to LDS (1 ds_write_b64/lane), chunk loop reads group-uniform ds_read_b128
// broadcasts (144B stride -> conflict-free), 4 gathers/chunk/group with a
// 2-deep chunk pipeline. Slots past degree padded s=0,w=0.
// ---------------------------------------------------------------------------
#define GROUPS_PER_BLOCK 16
#define LDS_STRIDE_B     144   // 16 slots * 8B + 16B pad (keeps b128 16B-aligned)

__global__ __launch_bounds__(256) void gather_sum_h(
    const half4v* __restrict__ xh,       // [N_NODES, 16] half4
    const float*  __restrict__ ev,
    const int*    __restrict__ src,
    const int*    __restrict__ row_ptr,
    float4*       __restrict__ out4)     // [N_NODES, 16] float4
{
    __shared__ char lds_raw[GROUPS_PER_BLOCK * LDS_STRIDE_B];

    const int tib  = threadIdx.x;
    const int gib  = tib >> 4;          // group within block: 0..15
    const int lane = tib & 15;          // lane within group
    const int node = blockIdx.x * GROUPS_PER_BLOCK + gib;
    if (node >= N_NODES) return;

    char* gbase = lds_raw + gib * LDS_STRIDE_B;

    const int start = row_ptr[node];
    const int end   = row_ptr[node + 1];

    float4 acc = make_float4(0.f, 0.f, 0.f, 0.f);

    for (int blk = start; blk < end; blk += 16) {
        const int bcnt = end - blk;          // >=1; clamp handled by padding

        // stage this block's (src, ev) pairs; pad unused slots with (0, 0.0f)
        int   s_ = 0; float w_ = 0.0f;
        if (lane < bcnt) { s_ = src[blk + lane]; w_ = ev[blk + lane]; }
        ((int2*)gbase)[lane] = make_int2(s_, __float_as_int(w_));

        const int nch = (min(bcnt, 16) + 3) >> 2;   // chunks of 4 edges

        // ---- chunk 0: meta broadcast + 4 gathers
        int4 m01 = ((const int4*)gbase)[0];   // s0,w0,s1,w1
        int4 m23 = ((const int4*)gbase)[1];   // s2,w2,s3,w3
        half4v x0 = xh[m01.x * 16 + lane];
        half4v x1 = xh[m01.z * 16 + lane];
        half4v x2 = xh[m23.x * 16 + lane];
        half4v x3 = xh[m23.z * 16 + lane];
        float w0 = __int_as_float(m01.y), w1 = __int_as_float(m01.w);
        float w2 = __int_as_float(m23.y), w3 = __int_as_float(m23.w);

        for (int c = 1; c < nch; ++c) {
            // next chunk: meta + gathers issued before consuming current
            int4 n01 = ((const int4*)gbase)[2 * c];
            int4 n23 = ((const int4*)gbase)[2 * c + 1];
            half4v nx0 = xh[n01.x * 16 + lane];
            half4v nx1 = xh[n01.z * 16 + lane];
            half4v nx2 = xh[n23.x * 16 + lane];
            half4v nx3 = xh[n23.z * 16 + lane];

            // consume current chunk
            acc.x = fmaf(w0, (float)x0.x, acc.x);
            acc.y = fmaf(w0, (float)x0.y, acc.y);
            acc.z = fmaf(w0, (float)x0.z, acc.z);
            acc.w = fmaf(w0, (float)x0.w, acc.w);
            acc.x = fmaf(w1, (float)x1.x, acc.x);
            acc.y = fmaf(w1, (float)x1.y, acc.y);
            acc.z = fmaf(w1, (float)x1.z, acc.z);
            acc.w = fmaf(w1, (float)x1.w, acc.w);
            acc.x = fmaf(w2, (float)x2.x, acc.x);
            acc.y = fmaf(w2, (float)x2.y, acc.y);
            acc.z = fmaf(w2, (float)x2.z, acc.z);
            acc.w = fmaf(w2, (float)x2.w, acc.w);
            acc.x = fmaf(w3, (float)x3.x, acc.x);
            acc.y = fmaf(w3, (float)x3.y, acc.y);
            acc.z = fmaf(w3, (float)x3.z, acc.z);
            acc.w = fmaf(w3, (float)x3.w, acc.w);

            x0 = nx0; x1 = nx1; x2 = nx2; x3 = nx3;
            w0 = __int_as_float(n01.y); w1 = __int_as_float(n01.w);
            w2 = __int_as_float(n23.y); w3 = __int_as_float(n23.w);
        }

        // consume final chunk
        acc.x = fmaf(w0, (float)x0.x, acc.x);
        acc.y = fmaf(w0, (float)x0.y, acc.y);
        acc.z = fmaf(w0, (float)x0.z, acc.z);
        acc.w = fmaf(w0, (float)x0.w, acc.w);
        acc.x = fmaf(w1, (float)x1.x, acc.x);
        acc.y = fmaf(w1, (float)x1.y, acc.y);
        acc.z = fmaf(w1, (float)x1.z, acc.z);
        acc.w = fmaf(w1, (float)x1.w, acc.w);
        acc.x = fmaf(w2, (float)x2.x, acc.x);
        acc.y = fmaf(w2, (float)x2.y, acc.y);
        acc.z = fmaf(w2, (float)x2.z, acc.z);
        acc.w = fmaf(w2, (float)x2.w, acc.w);
        acc.x = fmaf(w3, (float)x3.x, acc.x);
        acc.y = fmaf(w3, (float)x3.y, acc.y);
        acc.z = fmaf(w3, (float)x3.z, acc.z);
        acc.w = fmaf(w3, (float)x3.w, acc.w);
    }

    out4[node * 16 + lane] = acc;   // unconditional: empty nodes store 0
}

// fp32 fallback gather (R3 structure) if ws can't hold xh
__global__ __launch_bounds__(256) void gather_sum_f32(
    const float4* __restrict__ x4,
    const float*  __restrict__ ev,
    const int*    __restrict__ src,
    const int*    __restrict__ row_ptr,
    float4*       __restrict__ out4)
{
    const int node = blockIdx.x * 4 + (threadIdx.x >> 6);
    if (node >= N_NODES) return;
    const int lane = threadIdx.x & 63;
    const int g    = lane >> 4;
    const int f    = lane & 15;

    const int start = row_ptr[node];
    const int end   = row_ptr[node + 1];

    float4 acc = make_float4(0.f, 0.f, 0.f, 0.f);
    if (start < end) {
        int  ea = start + g, eb = start + 4 + g;
        bool va = ea < end,  vb = eb < end;
        int  esa = va ? ea : start, esb = vb ? eb : start;
        float wa = va ? ev[esa] : 0.0f;
        float wb = vb ? ev[esb] : 0.0f;
        int   sa = src[esa];
        int   sb = src[esb];

        for (int e0 = start; e0 < end; e0 += 8) {
            const float4 xa = x4[sa * 16 + f];
            const float4 xb = x4[sb * 16 + f];
            const float cwa = wa, cwb = wb;
            {
                int  na = e0 + 8 + g, nb = e0 + 12 + g;
                bool vna = na < end,  vnb = nb < end;
                int  nsa = vna ? na : start, nsb = vnb ? nb : start;
                wa = vna ? ev[nsa] : 0.0f;
                wb = vnb ? ev[nsb] : 0.0f;
                sa = src[nsa];
                sb = src[nsb];
            }
            acc.x = fmaf(cwa, xa.x, acc.x);
            acc.y = fmaf(cwa, xa.y, acc.y);
            acc.z = fmaf(cwa, xa.z, acc.z);
            acc.w = fmaf(cwa, xa.w, acc.w);
            acc.x = fmaf(cwb, xb.x, acc.x);
            acc.y = fmaf(cwb, xb.y, acc.y);
            acc.z = fmaf(cwb, xb.z, acc.z);
            acc.w = fmaf(cwb, xb.w, acc.w);
        }
    }
    acc.x += __shfl_xor(acc.x, 16, 64);
    acc.y += __shfl_xor(acc.y, 16, 64);
    acc.z += __shfl_xor(acc.z, 16, 64);
    acc.w += __shfl_xor(acc.w, 16, 64);
    acc.x += __shfl_xor(acc.x, 32, 64);
    acc.y += __shfl_xor(acc.y, 32, 64);
    acc.z += __shfl_xor(acc.z, 32, 64);
    acc.w += __shfl_xor(acc.w, 32, 64);
    if (g == 0) out4[node * 16 + f] = acc;
}

extern "C" void kernel_launch(void* const* d_in, const int* in_sizes, int n_in,
                              void* d_out, int out_size, void* d_ws, size_t ws_size,
                              hipStream_t stream) {
    const float* x            = (const float*)d_in[0];
    const float* edge_values  = (const float*)d_in[1];
    const int*   target_index = (const int*)d_in[2];
    const int*   source_index = (const int*)d_in[3];
    float*       out          = (float*)d_out;

    const size_t rp_bytes = (size_t)(N_NODES + 1) * sizeof(int);
    const size_t xh_off   = (rp_bytes + 511) & ~(size_t)511;
    const size_t xh_bytes = (size_t)N_NODES * D_FEAT * sizeof(_Float16); // 12.8 MB
    const size_t need     = xh_off + xh_bytes;

    int* row_ptr = (int*)d_ws;

    if (ws_size >= need) {
        half4v* xh = (half4v*)((char*)d_ws + xh_off);
        const int conv_blocks = (N_NODES * 16 + 255) / 256;          // 6250
        const int rp_blocks   = (N_EDGES + 255) / 256;               // 6250
        prep_kernel<<<conv_blocks + rp_blocks, 256, 0, stream>>>(
            (const float4*)x, target_index, xh, row_ptr, conv_blocks);

        const int n_blocks = (N_NODES + GROUPS_PER_BLOCK - 1) / GROUPS_PER_BLOCK;
        gather_sum_h<<<n_blocks, 256, 0, stream>>>(
            xh, edge_values, source_index, row_ptr, (float4*)out);
    } else {
        build_row_ptr<<<(N_EDGES + 255) / 256, 256, 0, stream>>>(target_index, row_ptr);
        gather_sum_f32<<<(N_NODES + 3) / 4, 256, 0, stream>>>(
            (const float4*)x, edge_values, source_index, row_ptr, (float4*)out);
    }
}